// Round 5
// baseline (194.509 us; speedup 1.0000x reference)
//
#include <hip/hip_runtime.h>
#include <stdint.h>

#define BATCH 16
#define CIN   64
#define COUT  64
#define NBR   8
#define HH    128
#define WW    128

typedef __attribute__((ext_vector_type(8)))  short short8;
typedef __attribute__((ext_vector_type(16))) float f32x16;

// round-half-up f32->bf16 (inputs are tame normals; 3.4x error headroom measured)
__device__ __forceinline__ unsigned int f2bf_hi(float f) {
    union { float f; uint32_t u; } v; v.f = f;
    return (v.u + 0x8000u) >> 16;
}
// RNE version
__device__ __forceinline__ unsigned short f2bf(float f) {
    union { float f; uint32_t u; } v; v.f = f;
    uint32_t u = v.u;
    return (unsigned short)((u + 0x7FFFu + ((u >> 16) & 1u)) >> 16);
}
__device__ __forceinline__ short8 gld_frag(const unsigned short* p) {
    union { uint4 u; short8 s; } t;
    t.u = *(const uint4*)p;            // 16B aligned
    return t.s;
}
__device__ __forceinline__ short8 lds_frag(const unsigned short* p) {
    union { uint2 u[2]; short8 s; } t;
    t.u[0] = *(const uint2*)p;         // 8B aligned
    t.u[1] = *(const uint2*)(p + 4);
    return t.s;
}

// ---------------- kernel 1: softmax + filter/bias combine (1024 blocks) ----------------
__global__ __launch_bounds__(256)
void k_prep(const float* __restrict__ cond,
            const float* __restrict__ sel_w,
            const float* __restrict__ sel_b,
            const float* __restrict__ filt_w,
            const float* __restrict__ filt_b,
            unsigned short* __restrict__ wfilt,
            float* __restrict__ cbias) {
    __shared__ float4 lw4[NBR * 144];          // 8 x 576 floats = 18432 B
    __shared__ float lg[NBR];
    float* lw = (float*)lw4;

    const int blk = blockIdx.x;                // 1024
    const int b = blk >> 6, o = blk & 63;
    const int tid = threadIdx.x;

    const float4* src4 = (const float4*)filt_w;
    #pragma unroll
    for (int i = tid; i < NBR * 144; i += 256)
        lw4[i] = src4[((i / 144) * COUT + o) * 144 + (i % 144)];

    {
        const int lane = tid & 63, w = tid >> 6;
        const float c0 = cond[b * CIN + lane];
        #pragma unroll
        for (int k = 0; k < 2; ++k) {
            const int n = w + k * 4;
            float p = c0 * sel_w[n * CIN + lane];
            #pragma unroll
            for (int off = 32; off > 0; off >>= 1)
                p += __shfl_down(p, off, 64);
            if (lane == 0) lg[n] = p + sel_b[n];
        }
    }
    __syncthreads();

    float w8[NBR];
    {
        float m = -1e30f;
        #pragma unroll
        for (int n = 0; n < NBR; ++n) m = fmaxf(m, lg[n]);
        float s = 0.f;
        #pragma unroll
        for (int n = 0; n < NBR; ++n) { w8[n] = __expf(lg[n] - m); s += w8[n]; }
        const float inv = 1.f / s;
        #pragma unroll
        for (int n = 0; n < NBR; ++n) w8[n] *= inv;
    }

    #pragma unroll
    for (int idx = tid; idx < 576; idx += 256) {
        const int t = idx >> 6, c = idx & 63;
        float acc = 0.f;
        #pragma unroll
        for (int n = 0; n < NBR; ++n)
            acc += w8[n] * lw[n * 576 + c * 9 + t];
        wfilt[(((long)(b * 9 + t) * COUT + o) << 6) + c] = f2bf(acc);
    }
    if (tid == 0) {
        float ab = 0.f;
        #pragma unroll
        for (int n = 0; n < NBR; ++n) ab += w8[n] * filt_b[n * COUT + o];
        cbias[b * COUT + o] = ab;
    }
}

// ---------------- kernel 2: fused conv, pipelined staging + tap-prefetch ----------------
#define RT 8
#define WT 32
#define SLABW 34          // WT + 2 halo
#define SLABR 10          // RT + 2 halo
#define PSTR  68          // ushorts per pixel (64 ch + 4 pad)
#define NTASK (SLABR * 32 * 10)   // 3200

__global__ __launch_bounds__(256, 3)
void k_conv5(const float* __restrict__ x,
             const unsigned short* __restrict__ wfilt,
             const float* __restrict__ cbias,
             float* __restrict__ out) {
    __shared__ unsigned short lx[SLABR * SLABW * PSTR];   // 46240 B

    const int b  = blockIdx.z;
    const int h0 = blockIdx.y * RT;
    const int w0 = blockIdx.x * WT;
    const int tid = threadIdx.x;

    const int lane = tid & 63;
    const int wave = tid >> 6;
    const int l31  = lane & 31;
    const int lh   = lane >> 5;
    const int r0   = wave * 2;

    const unsigned short* wf = wfilt + (long)b * 9 * COUT * CIN;

    // issue tap-0 A-fragment loads first: overlap with ALL of staging
    short8 A0[4], A1[4];
    #pragma unroll
    for (int cc = 0; cc < 4; ++cc) {
        A0[cc] = gld_frag(wf + l31 * CIN + cc * 16 + lh * 8);
        A1[cc] = gld_frag(wf + (32 + l31) * CIN + cc * 16 + lh * 8);
    }

    // ---- staging: two register-batched, compile-time-unrolled passes ----
    // task = (s, channel-pair cp, j): float4 of 4 w-pixels for channels c,c+1
    {
        float4 va[7], vb[7];
        // pass 1: it = 0..6 (all tasks < 3200, no task guard)
        #pragma unroll
        for (int it = 0; it < 7; ++it) {
            const int task = tid + it * 256;
            const int j = task % 10, r = task / 10;
            const int c = (r & 31) * 2, s = r >> 5;
            const int hin = h0 + s - 1, wbase = w0 - 4 + j * 4;
            float4 z; z.x = z.y = z.z = z.w = 0.f;
            va[it] = z; vb[it] = z;
            if (hin >= 0 && hin < HH && wbase >= 0 && wbase < WW) {
                const float* px = x + (((long)(b * CIN + c) * HH + hin) * WW + wbase);
                va[it] = *(const float4*)px;
                vb[it] = *(const float4*)(px + (long)HH * WW);
            }
        }
        #pragma unroll
        for (int it = 0; it < 7; ++it) {
            const int task = tid + it * 256;
            const int j = task % 10, r = task / 10;
            const int c = (r & 31) * 2, s = r >> 5;
            unsigned int d[4];
            d[0] = f2bf_hi(va[it].x) | (f2bf_hi(vb[it].x) << 16);
            d[1] = f2bf_hi(va[it].y) | (f2bf_hi(vb[it].y) << 16);
            d[2] = f2bf_hi(va[it].z) | (f2bf_hi(vb[it].z) << 16);
            d[3] = f2bf_hi(va[it].w) | (f2bf_hi(vb[it].w) << 16);
            #pragma unroll
            for (int i = 0; i < 4; ++i) {
                const int p = j * 4 - 3 + i;
                if (p >= 0 && p < SLABW)
                    *(unsigned int*)&lx[(s * SLABW + p) * PSTR + c] = d[i];
            }
        }
        // pass 2: it = 7..12 (it==12 needs task < 3200, i.e. tid < 128)
        #pragma unroll
        for (int it = 0; it < 6; ++it) {
            const int task = tid + (it + 7) * 256;
            const int j = task % 10, r = task / 10;
            const int c = (r & 31) * 2, s = r >> 5;
            const int hin = h0 + s - 1, wbase = w0 - 4 + j * 4;
            float4 z; z.x = z.y = z.z = z.w = 0.f;
            va[it] = z; vb[it] = z;
            if (task < NTASK && hin >= 0 && hin < HH && wbase >= 0 && wbase < WW) {
                const float* px = x + (((long)(b * CIN + c) * HH + hin) * WW + wbase);
                va[it] = *(const float4*)px;
                vb[it] = *(const float4*)(px + (long)HH * WW);
            }
        }
        #pragma unroll
        for (int it = 0; it < 6; ++it) {
            const int task = tid + (it + 7) * 256;
            if (task < NTASK) {
                const int j = task % 10, r = task / 10;
                const int c = (r & 31) * 2, s = r >> 5;
                unsigned int d[4];
                d[0] = f2bf_hi(va[it].x) | (f2bf_hi(vb[it].x) << 16);
                d[1] = f2bf_hi(va[it].y) | (f2bf_hi(vb[it].y) << 16);
                d[2] = f2bf_hi(va[it].z) | (f2bf_hi(vb[it].z) << 16);
                d[3] = f2bf_hi(va[it].w) | (f2bf_hi(vb[it].w) << 16);
                #pragma unroll
                for (int i = 0; i < 4; ++i) {
                    const int p = j * 4 - 3 + i;
                    if (p >= 0 && p < SLABW)
                        *(unsigned int*)&lx[(s * SLABW + p) * PSTR + c] = d[i];
                }
            }
        }
    }

    // bias-initialized accumulators (C/D row m = (i&3)+8*(i>>2)+4*lh)
    f32x16 acc00, acc01, acc10, acc11;
    #pragma unroll
    for (int i = 0; i < 16; ++i) {
        const int m = (i & 3) + 8 * (i >> 2) + 4 * lh;
        const float b0 = cbias[b * COUT + m];
        const float b1 = cbias[b * COUT + 32 + m];
        acc00[i] = b0; acc01[i] = b0;
        acc10[i] = b1; acc11[i] = b1;
    }

    __syncthreads();

    #pragma unroll
    for (int tap = 0; tap < 9; ++tap) {
        short8 nA0[4], nA1[4];
        if (tap < 8) {
            const unsigned short* wn = wf + (long)(tap + 1) * COUT * CIN;
            #pragma unroll
            for (int cc = 0; cc < 4; ++cc) {
                nA0[cc] = gld_frag(wn + l31 * CIN + cc * 16 + lh * 8);
                nA1[cc] = gld_frag(wn + (32 + l31) * CIN + cc * 16 + lh * 8);
            }
        }
        const int kh = tap / 3, kw = tap % 3;
        #pragma unroll
        for (int cc = 0; cc < 4; ++cc) {
            const int kofs = cc * 16 + lh * 8;
            short8 b0 = lds_frag(&lx[((r0     + kh) * SLABW + l31 + kw) * PSTR + kofs]);
            short8 b1 = lds_frag(&lx[((r0 + 1 + kh) * SLABW + l31 + kw) * PSTR + kofs]);
            acc00 = __builtin_amdgcn_mfma_f32_32x32x16_bf16(A0[cc], b0, acc00, 0, 0, 0);
            acc01 = __builtin_amdgcn_mfma_f32_32x32x16_bf16(A0[cc], b1, acc01, 0, 0, 0);
            acc10 = __builtin_amdgcn_mfma_f32_32x32x16_bf16(A1[cc], b0, acc10, 0, 0, 0);
            acc11 = __builtin_amdgcn_mfma_f32_32x32x16_bf16(A1[cc], b1, acc11, 0, 0, 0);
        }
        #pragma unroll
        for (int cc = 0; cc < 4; ++cc) { A0[cc] = nA0[cc]; A1[cc] = nA1[cc]; }
    }

    #pragma unroll
    for (int cb = 0; cb < 2; ++cb) {
        #pragma unroll
        for (int pb = 0; pb < 2; ++pb) {
            const f32x16 v = cb == 0 ? (pb == 0 ? acc00 : acc01)
                                     : (pb == 0 ? acc10 : acc11);
            const int hrow = h0 + r0 + pb;
            float* op = out + (((long)(b * COUT + cb * 32) * HH + hrow) * WW + w0 + l31);
            #pragma unroll
            for (int i = 0; i < 16; ++i) {
                const int m = (i & 3) + 8 * (i >> 2) + 4 * lh;
                op[(long)m * HH * WW] = v[i];
            }
        }
    }
}

extern "C" void kernel_launch(void* const* d_in, const int* in_sizes, int n_in,
                              void* d_out, int out_size, void* d_ws, size_t ws_size,
                              hipStream_t stream) {
    const float* x      = (const float*)d_in[0];
    const float* cond   = (const float*)d_in[1];
    const float* filt_w = (const float*)d_in[2];
    const float* filt_b = (const float*)d_in[3];
    const float* sel_w  = (const float*)d_in[4];
    const float* sel_b  = (const float*)d_in[5];
    float* out = (float*)d_out;

    // ws: cbias [16][64] f32 @0; wfilt [16][9][64][64] bf16 @4096
    float*          cbias = (float*)d_ws;
    unsigned short* wfilt = (unsigned short*)((char*)d_ws + 4096);

    k_prep<<<BATCH * COUT, 256, 0, stream>>>(cond, sel_w, sel_b, filt_w, filt_b, wfilt, cbias);

    dim3 grid(WW / WT, HH / RT, BATCH);                  // 4 x 16 x 16 = 1024 blocks
    k_conv5<<<grid, 256, 0, stream>>>(x, wfilt, cbias, out);
}